// Round 3
// baseline (543.744 us; speedup 1.0000x reference)
//
#include <hip/hip_runtime.h>

// CoordinateDescent: one Gauss-Seidel sweep for u (vs x@v, v^T v), then for v
// (vs x^T@u_new, u_new^T u_new). B=4, M=N=4096, R=16, fp32.
constexpr int B = 4, M = 4096, N = 4096, R = 16;
constexpr float EPS = 1e-8f;
constexpr int GCH = 64;   // n-chunks for gram partials
constexpr int ACH = 16;   // m-chunks for x^T@u partials

// ---- b = w^T w partials: part[b][c][t] with t = r2*16 + r1 ----
__global__ void gram_partial(const float* __restrict__ w, float* __restrict__ part, int L) {
  const int b = blockIdx.y, c = blockIdx.x, t = threadIdx.x;
  const int r1 = t & 15, r2 = t >> 4;
  const float* wb = w + (size_t)b * L * R;
  const int span = L / GCH;
  const int n0 = c * span;
  float s = 0.f;
  for (int n = n0; n < n0 + span; ++n)
    s = fmaf(wb[(size_t)n * R + r1], wb[(size_t)n * R + r2], s);
  part[((b * GCH + c) << 8) + t] = s;
}

// ---- a1 = x @ v : wave handles 4 rows, lanes split n, butterfly reduce ----
// 4 rows/wave keeps VGPR ~140 (no spill); grid = 1024 blocks -> 3 blocks/CU.
__launch_bounds__(256, 3)
__global__ void xv_kernel(const float* __restrict__ x, const float* __restrict__ v,
                          float* __restrict__ a1) {
  const int b = blockIdx.y;
  const int wave = threadIdx.x >> 6;
  const int lane = threadIdx.x & 63;
  const int m0 = blockIdx.x * 16 + wave * 4;
  const float* xb = x + ((size_t)b * M + m0) * N;
  const float* vb = v + (size_t)b * N * R;

  float acc[4][16];
#pragma unroll
  for (int i = 0; i < 4; ++i)
#pragma unroll
    for (int r = 0; r < 16; ++r) acc[i][r] = 0.f;

#pragma unroll 2
  for (int k = 0; k < 16; ++k) {
    const int nb = k * 256 + lane * 4;
    float4 xr[4];
#pragma unroll
    for (int mi = 0; mi < 4; ++mi)
      xr[mi] = *(const float4*)(xb + (size_t)mi * N + nb);
#pragma unroll
    for (int j = 0; j < 4; ++j) {
      const float* vp = vb + (size_t)(nb + j) * R;
      const float4 v0 = *(const float4*)(vp + 0);
      const float4 v1 = *(const float4*)(vp + 4);
      const float4 v2 = *(const float4*)(vp + 8);
      const float4 v3 = *(const float4*)(vp + 12);
      const float vv[16] = {v0.x, v0.y, v0.z, v0.w, v1.x, v1.y, v1.z, v1.w,
                            v2.x, v2.y, v2.z, v2.w, v3.x, v3.y, v3.z, v3.w};
#pragma unroll
      for (int mi = 0; mi < 4; ++mi) {
        const float xs = (j == 0) ? xr[mi].x : (j == 1) ? xr[mi].y
                                             : (j == 2) ? xr[mi].z : xr[mi].w;
#pragma unroll
        for (int r = 0; r < 16; ++r)
          acc[mi][r] = fmaf(xs, vv[r], acc[mi][r]);
      }
    }
  }

  // full 64-lane butterfly; every lane ends with the row sum, lane 0 stores.
#pragma unroll
  for (int mi = 0; mi < 4; ++mi)
#pragma unroll
    for (int r = 0; r < 16; ++r) {
      float s = acc[mi][r];
      s += __shfl_xor(s, 1);
      s += __shfl_xor(s, 2);
      s += __shfl_xor(s, 4);
      s += __shfl_xor(s, 8);
      s += __shfl_xor(s, 16);
      s += __shfl_xor(s, 32);
      acc[mi][r] = s;
    }
  if (lane == 0) {
#pragma unroll
    for (int mi = 0; mi < 4; ++mi) {
      float* ap = a1 + ((size_t)b * M + m0 + mi) * R;
      *(float4*)(ap + 0)  = make_float4(acc[mi][0],  acc[mi][1],  acc[mi][2],  acc[mi][3]);
      *(float4*)(ap + 4)  = make_float4(acc[mi][4],  acc[mi][5],  acc[mi][6],  acc[mi][7]);
      *(float4*)(ap + 8)  = make_float4(acc[mi][8],  acc[mi][9],  acc[mi][10], acc[mi][11]);
      *(float4*)(ap + 12) = make_float4(acc[mi][12], acc[mi][13], acc[mi][14], acc[mi][15]);
    }
  }
}

// ---- a2 partials: part[mc][b][n][r] = sum_{m in chunk} x[b][m][n] * u[b][m][r] ----
// ACH=16 -> 1024 blocks (4 blocks/CU); unroll 8 -> 32 KB/CU x-loads in flight.
__launch_bounds__(256, 4)
__global__ void xtu_partial(const float* __restrict__ x, const float* __restrict__ u,
                            float* __restrict__ part) {
  const int strip = blockIdx.x;  // 16 strips of 256 n
  const int mc = blockIdx.y;     // ACH chunks of M/ACH rows
  const int b = blockIdx.z;
  const int t = threadIdx.x;
  const int n = strip * 256 + t;
  const float* xb = x + (size_t)b * M * N + n;
  const float* ub = u + (size_t)b * M * R;

  float acc[16];
#pragma unroll
  for (int r = 0; r < 16; ++r) acc[r] = 0.f;

  const int mstart = mc * (M / ACH);
  const int mend = mstart + (M / ACH);
#pragma unroll 8
  for (int m = mstart; m < mend; ++m) {
    const float xs = xb[(size_t)m * N];
    const float4 u0 = *(const float4*)(ub + (size_t)m * R + 0);
    const float4 u1 = *(const float4*)(ub + (size_t)m * R + 4);
    const float4 u2 = *(const float4*)(ub + (size_t)m * R + 8);
    const float4 u3 = *(const float4*)(ub + (size_t)m * R + 12);
    acc[0]  = fmaf(xs, u0.x, acc[0]);  acc[1]  = fmaf(xs, u0.y, acc[1]);
    acc[2]  = fmaf(xs, u0.z, acc[2]);  acc[3]  = fmaf(xs, u0.w, acc[3]);
    acc[4]  = fmaf(xs, u1.x, acc[4]);  acc[5]  = fmaf(xs, u1.y, acc[5]);
    acc[6]  = fmaf(xs, u1.z, acc[6]);  acc[7]  = fmaf(xs, u1.w, acc[7]);
    acc[8]  = fmaf(xs, u2.x, acc[8]);  acc[9]  = fmaf(xs, u2.y, acc[9]);
    acc[10] = fmaf(xs, u2.z, acc[10]); acc[11] = fmaf(xs, u2.w, acc[11]);
    acc[12] = fmaf(xs, u3.x, acc[12]); acc[13] = fmaf(xs, u3.y, acc[13]);
    acc[14] = fmaf(xs, u3.z, acc[14]); acc[15] = fmaf(xs, u3.w, acc[15]);
  }
  float* p = part + (((size_t)mc * B + b) * N + n) * R;
  *(float4*)(p + 0)  = make_float4(acc[0],  acc[1],  acc[2],  acc[3]);
  *(float4*)(p + 4)  = make_float4(acc[4],  acc[5],  acc[6],  acc[7]);
  *(float4*)(p + 8)  = make_float4(acc[8],  acc[9],  acc[10], acc[11]);
  *(float4*)(p + 12) = make_float4(acc[12], acc[13], acc[14], acc[15]);
}

// ---- Gauss-Seidel sweep, thread-per-row; sums gram partials into LDS and
//      (for the v-pass) sums ACH a-partials inline. ----
__global__ void cd_update(const float* __restrict__ aparts, int naparts,
                          const float* __restrict__ gparts,
                          const float* __restrict__ w_old, float* __restrict__ w_new,
                          int L) {
  __shared__ float bm[256];  // bm[s*16 + r] = b[s][r]
  const int b = blockIdx.y, t = threadIdx.x;
  float g = 0.f;
  for (int c = 0; c < GCH; ++c) g += gparts[((b * GCH + c) << 8) + t];
  bm[t] = g;
  __syncthreads();

  const int row = blockIdx.x * 256 + t;
  const size_t apart_stride = (size_t)B * L * R;
  const float* ap = aparts + ((size_t)b * L + row) * R;

  float a[16];
#pragma unroll
  for (int r = 0; r < 16; ++r) a[r] = 0.f;
  for (int c = 0; c < naparts; ++c) {
#pragma unroll
    for (int rr = 0; rr < 4; ++rr) {
      const float4 av = *(const float4*)(ap + (size_t)c * apart_stride + rr * 4);
      a[rr * 4 + 0] += av.x; a[rr * 4 + 1] += av.y;
      a[rr * 4 + 2] += av.z; a[rr * 4 + 3] += av.w;
    }
  }

  const float* wp = w_old + ((size_t)b * L + row) * R;
  float u[16];
#pragma unroll
  for (int rr = 0; rr < 4; ++rr) {
    const float4 wv = *(const float4*)(wp + rr * 4);
    u[rr * 4 + 0] = wv.x; u[rr * 4 + 1] = wv.y;
    u[rr * 4 + 2] = wv.z; u[rr * 4 + 3] = wv.w;
  }

#pragma unroll
  for (int r = 0; r < 16; ++r) {
    float cross = 0.f;
#pragma unroll
    for (int s = 0; s < 16; ++s)
      if (s != r) cross = fmaf(u[s], bm[s * 16 + r], cross);
    u[r] = (a[r] - cross + EPS) / (bm[r * 16 + r] + EPS);
  }

  float* op = w_new + ((size_t)b * L + row) * R;
  *(float4*)(op + 0)  = make_float4(u[0],  u[1],  u[2],  u[3]);
  *(float4*)(op + 4)  = make_float4(u[4],  u[5],  u[6],  u[7]);
  *(float4*)(op + 8)  = make_float4(u[8],  u[9],  u[10], u[11]);
  *(float4*)(op + 12) = make_float4(u[12], u[13], u[14], u[15]);
}

extern "C" void kernel_launch(void* const* d_in, const int* in_sizes, int n_in,
                              void* d_out, int out_size, void* d_ws, size_t ws_size,
                              hipStream_t stream) {
  (void)in_sizes; (void)n_in; (void)out_size; (void)ws_size;
  const float* x = (const float*)d_in[0];
  const float* u = (const float*)d_in[1];
  const float* v = (const float*)d_in[2];
  float* u_new = (float*)d_out;                        // B*M*R
  float* v_new = (float*)d_out + (size_t)B * M * R;    // B*N*R

  float* ws  = (float*)d_ws;
  float* a1  = ws;                                     // B*M*R         =  262144 f
  float* b1p = a1 + (size_t)B * M * R;                 // B*GCH*256     =   65536 f
  float* b2p = b1p + (size_t)B * GCH * 256;            //               =   65536 f
  float* a2p = b2p + (size_t)B * GCH * 256;            // ACH*B*N*R     = 4194304 f

  // pass 1: u_new = GS(x@v, u, v^T v)
  hipLaunchKernelGGL(gram_partial, dim3(GCH, B), dim3(256), 0, stream, v, b1p, N);
  hipLaunchKernelGGL(xv_kernel, dim3(M / 16, B), dim3(256), 0, stream, x, v, a1);
  hipLaunchKernelGGL(cd_update, dim3(M / 256, B), dim3(256), 0, stream,
                     a1, 1, b1p, u, u_new, M);
  // pass 2: v_new = GS(x^T@u_new, v, u_new^T u_new)
  hipLaunchKernelGGL(gram_partial, dim3(GCH, B), dim3(256), 0, stream, u_new, b2p, M);
  hipLaunchKernelGGL(xtu_partial, dim3(16, ACH, B), dim3(256), 0, stream, x, u_new, a2p);
  hipLaunchKernelGGL(cd_update, dim3(N / 256, B), dim3(256), 0, stream,
                     a2p, ACH, b2p, v, v_new, N);
}

// Round 5
// 483.260 us; speedup vs baseline: 1.1252x; 1.1252x over previous
//
#include <hip/hip_runtime.h>

// CoordinateDescent: one Gauss-Seidel sweep for u (vs x@v, v^T v), then for v
// (vs x^T@u_new, u_new^T u_new). B=4, M=N=4096, R=16, fp32.
constexpr int B = 4, M = 4096, N = 4096, R = 16;
constexpr float EPS = 1e-8f;
constexpr int GCH = 64;   // n-chunks for gram partials
constexpr int ACH = 16;   // m-chunks for x^T@u partials
constexpr int MCH = M / ACH;  // 256 rows per xtu chunk
constexpr int NK = 256;   // n per LDS tile in xv

// ---- b = w^T w partials: part[b][c][t] with t = r2*16 + r1 ----
__global__ void gram_partial(const float* __restrict__ w, float* __restrict__ part, int L) {
  const int b = blockIdx.y, c = blockIdx.x, t = threadIdx.x;
  const int r1 = t & 15, r2 = t >> 4;
  const float* wb = w + (size_t)b * L * R;
  const int span = L / GCH;
  const int n0 = c * span;
  float s = 0.f;
  for (int n = n0; n < n0 + span; ++n)
    s = fmaf(wb[(size_t)n * R + r1], wb[(size_t)n * R + r2], s);
  part[((b * GCH + c) << 8) + t] = s;
}

// ---- a1 = x @ v : v-tile staged in LDS transposed; lanes split n. ----
// Per k-tile: coalesced stage of vT[16][NK] (pad +1), then each lane reads
// vT[r][lane*4..+3] (bank-uniform b128) against float4 x loads.
__launch_bounds__(256, 4)
__global__ void xv_kernel(const float* __restrict__ x, const float* __restrict__ v,
                          float* __restrict__ a1) {
  __shared__ float vT[16][NK + 1];
  const int b = blockIdx.y;
  const int t = threadIdx.x;
  const int wave = t >> 6;
  const int lane = t & 63;
  const int m0 = blockIdx.x * 16 + wave * 4;
  const float* xb = x + ((size_t)b * M + m0) * N;
  const float* vb = v + (size_t)b * N * R;

  float acc[4][16];
#pragma unroll
  for (int i = 0; i < 4; ++i)
#pragma unroll
    for (int r = 0; r < 16; ++r) acc[i][r] = 0.f;

  for (int k = 0; k < N / NK; ++k) {
    const int nb = k * NK;
    __syncthreads();  // previous tile's reads complete before overwrite
#pragma unroll
    for (int q = 0; q < 4; ++q) {
      const int f = t + 256 * q;         // float4 index within 16 KB tile
      const int row = f >> 2;            // 0..255
      const int e = (f & 3) * 4;         // 0,4,8,12
      const float4 val = *(const float4*)(vb + (size_t)(nb + row) * R + e);
      vT[e + 0][row] = val.x;
      vT[e + 1][row] = val.y;
      vT[e + 2][row] = val.z;
      vT[e + 3][row] = val.w;
    }
    __syncthreads();

    const int nl = lane * 4;
    float4 xr[4];
#pragma unroll
    for (int mi = 0; mi < 4; ++mi)
      xr[mi] = *(const float4*)(xb + (size_t)mi * N + nb + nl);
#pragma unroll
    for (int r = 0; r < 16; ++r) {
      const float4 vv = *(const float4*)&vT[r][nl];
#pragma unroll
      for (int mi = 0; mi < 4; ++mi) {
        acc[mi][r] = fmaf(xr[mi].x, vv.x, acc[mi][r]);
        acc[mi][r] = fmaf(xr[mi].y, vv.y, acc[mi][r]);
        acc[mi][r] = fmaf(xr[mi].z, vv.z, acc[mi][r]);
        acc[mi][r] = fmaf(xr[mi].w, vv.w, acc[mi][r]);
      }
    }
  }

  // full 64-lane butterfly; every lane ends with the row sum, lane 0 stores.
#pragma unroll
  for (int mi = 0; mi < 4; ++mi)
#pragma unroll
    for (int r = 0; r < 16; ++r) {
      float s = acc[mi][r];
      s += __shfl_xor(s, 1);
      s += __shfl_xor(s, 2);
      s += __shfl_xor(s, 4);
      s += __shfl_xor(s, 8);
      s += __shfl_xor(s, 16);
      s += __shfl_xor(s, 32);
      acc[mi][r] = s;
    }
  if (lane == 0) {
#pragma unroll
    for (int mi = 0; mi < 4; ++mi) {
      float* ap = a1 + ((size_t)b * M + m0 + mi) * R;
      *(float4*)(ap + 0)  = make_float4(acc[mi][0],  acc[mi][1],  acc[mi][2],  acc[mi][3]);
      *(float4*)(ap + 4)  = make_float4(acc[mi][4],  acc[mi][5],  acc[mi][6],  acc[mi][7]);
      *(float4*)(ap + 8)  = make_float4(acc[mi][8],  acc[mi][9],  acc[mi][10], acc[mi][11]);
      *(float4*)(ap + 12) = make_float4(acc[mi][12], acc[mi][13], acc[mi][14], acc[mi][15]);
    }
  }
}

// ---- a2 partials: part[mc][b][n][r] = sum_{m in chunk} x[b][m][n] * u[b][m][r] ----
// u-chunk (16 KB) staged once per block in LDS; inner loop reads it via
// uniform-address (broadcast) ds_read_b128. x loads coalesced, unroll 8.
__launch_bounds__(256, 4)
__global__ void xtu_partial(const float* __restrict__ x, const float* __restrict__ u,
                            float* __restrict__ part) {
  __shared__ float4 us4[MCH * 4];  // MCH rows x 16 floats = 16 KB
  const int strip = blockIdx.x;    // 16 strips of 256 n
  const int mc = blockIdx.y;       // ACH chunks of MCH rows
  const int b = blockIdx.z;
  const int t = threadIdx.x;
  const int n = strip * 256 + t;
  const float* xb = x + (size_t)b * M * N + n;
  const int mstart = mc * MCH;
  const float4* ub4 = (const float4*)(u + (size_t)b * M * R) + (size_t)mstart * 4;

#pragma unroll
  for (int q = 0; q < 4; ++q)
    us4[t + 256 * q] = ub4[t + 256 * q];
  __syncthreads();

  float acc[16];
#pragma unroll
  for (int r = 0; r < 16; ++r) acc[r] = 0.f;

#pragma unroll 8
  for (int ml = 0; ml < MCH; ++ml) {
    const float xs = xb[(size_t)(mstart + ml) * N];
    const float4 u0 = us4[ml * 4 + 0];
    const float4 u1 = us4[ml * 4 + 1];
    const float4 u2 = us4[ml * 4 + 2];
    const float4 u3 = us4[ml * 4 + 3];
    acc[0]  = fmaf(xs, u0.x, acc[0]);  acc[1]  = fmaf(xs, u0.y, acc[1]);
    acc[2]  = fmaf(xs, u0.z, acc[2]);  acc[3]  = fmaf(xs, u0.w, acc[3]);
    acc[4]  = fmaf(xs, u1.x, acc[4]);  acc[5]  = fmaf(xs, u1.y, acc[5]);
    acc[6]  = fmaf(xs, u1.z, acc[6]);  acc[7]  = fmaf(xs, u1.w, acc[7]);
    acc[8]  = fmaf(xs, u2.x, acc[8]);  acc[9]  = fmaf(xs, u2.y, acc[9]);
    acc[10] = fmaf(xs, u2.z, acc[10]); acc[11] = fmaf(xs, u2.w, acc[11]);
    acc[12] = fmaf(xs, u3.x, acc[12]); acc[13] = fmaf(xs, u3.y, acc[13]);
    acc[14] = fmaf(xs, u3.z, acc[14]); acc[15] = fmaf(xs, u3.w, acc[15]);
  }
  float* p = part + (((size_t)mc * B + b) * N + n) * R;
  *(float4*)(p + 0)  = make_float4(acc[0],  acc[1],  acc[2],  acc[3]);
  *(float4*)(p + 4)  = make_float4(acc[4],  acc[5],  acc[6],  acc[7]);
  *(float4*)(p + 8)  = make_float4(acc[8],  acc[9],  acc[10], acc[11]);
  *(float4*)(p + 12) = make_float4(acc[12], acc[13], acc[14], acc[15]);
}

// ---- Gauss-Seidel sweep, thread-per-row; sums gram partials into LDS and
//      (for the v-pass) sums ACH a-partials inline. ----
__global__ void cd_update(const float* __restrict__ aparts, int naparts,
                          const float* __restrict__ gparts,
                          const float* __restrict__ w_old, float* __restrict__ w_new,
                          int L) {
  __shared__ float bm[256];  // bm[s*16 + r] = b[s][r]
  const int b = blockIdx.y, t = threadIdx.x;
  float g = 0.f;
  for (int c = 0; c < GCH; ++c) g += gparts[((b * GCH + c) << 8) + t];
  bm[t] = g;
  __syncthreads();

  const int row = blockIdx.x * 256 + t;
  const size_t apart_stride = (size_t)B * L * R;
  const float* ap = aparts + ((size_t)b * L + row) * R;

  float a[16];
#pragma unroll
  for (int r = 0; r < 16; ++r) a[r] = 0.f;
  for (int c = 0; c < naparts; ++c) {
#pragma unroll
    for (int rr = 0; rr < 4; ++rr) {
      const float4 av = *(const float4*)(ap + (size_t)c * apart_stride + rr * 4);
      a[rr * 4 + 0] += av.x; a[rr * 4 + 1] += av.y;
      a[rr * 4 + 2] += av.z; a[rr * 4 + 3] += av.w;
    }
  }

  const float* wp = w_old + ((size_t)b * L + row) * R;
  float u[16];
#pragma unroll
  for (int rr = 0; rr < 4; ++rr) {
    const float4 wv = *(const float4*)(wp + rr * 4);
    u[rr * 4 + 0] = wv.x; u[rr * 4 + 1] = wv.y;
    u[rr * 4 + 2] = wv.z; u[rr * 4 + 3] = wv.w;
  }

#pragma unroll
  for (int r = 0; r < 16; ++r) {
    float cross = 0.f;
#pragma unroll
    for (int s = 0; s < 16; ++s)
      if (s != r) cross = fmaf(u[s], bm[s * 16 + r], cross);
    u[r] = (a[r] - cross + EPS) / (bm[r * 16 + r] + EPS);
  }

  float* op = w_new + ((size_t)b * L + row) * R;
  *(float4*)(op + 0)  = make_float4(u[0],  u[1],  u[2],  u[3]);
  *(float4*)(op + 4)  = make_float4(u[4],  u[5],  u[6],  u[7]);
  *(float4*)(op + 8)  = make_float4(u[8],  u[9],  u[10], u[11]);
  *(float4*)(op + 12) = make_float4(u[12], u[13], u[14], u[15]);
}

extern "C" void kernel_launch(void* const* d_in, const int* in_sizes, int n_in,
                              void* d_out, int out_size, void* d_ws, size_t ws_size,
                              hipStream_t stream) {
  (void)in_sizes; (void)n_in; (void)out_size; (void)ws_size;
  const float* x = (const float*)d_in[0];
  const float* u = (const float*)d_in[1];
  const float* v = (const float*)d_in[2];
  float* u_new = (float*)d_out;                        // B*M*R
  float* v_new = (float*)d_out + (size_t)B * M * R;    // B*N*R

  float* ws  = (float*)d_ws;
  float* a1  = ws;                                     // B*M*R         =  262144 f
  float* b1p = a1 + (size_t)B * M * R;                 // B*GCH*256     =   65536 f
  float* b2p = b1p + (size_t)B * GCH * 256;            //               =   65536 f
  float* a2p = b2p + (size_t)B * GCH * 256;            // ACH*B*N*R     = 4194304 f

  // pass 1: u_new = GS(x@v, u, v^T v)
  hipLaunchKernelGGL(gram_partial, dim3(GCH, B), dim3(256), 0, stream, v, b1p, N);
  hipLaunchKernelGGL(xv_kernel, dim3(M / 16, B), dim3(256), 0, stream, x, v, a1);
  hipLaunchKernelGGL(cd_update, dim3(M / 256, B), dim3(256), 0, stream,
                     a1, 1, b1p, u, u_new, M);
  // pass 2: v_new = GS(x^T@u_new, v, u_new^T u_new)
  hipLaunchKernelGGL(gram_partial, dim3(GCH, B), dim3(256), 0, stream, u_new, b2p, M);
  hipLaunchKernelGGL(xtu_partial, dim3(16, ACH, B), dim3(256), 0, stream, x, u_new, a2p);
  hipLaunchKernelGGL(cd_update, dim3(N / 256, B), dim3(256), 0, stream,
                     a2p, ACH, b2p, v, v_new, N);
}